// Round 4
// baseline (478.597 us; speedup 1.0000x reference)
//
#include <hip/hip_runtime.h>
#include <math.h>

#define NUM_USERS 100000
#define NUM_ITEMS 50000
#define EMBED     64
#define NUM_EDGES 3276800
#define BATCH     16384
#define CAP       12800       // pass1 padded mean ~11380 + ~11 sigma; pass2 pad16 compacted fits
#define NBUCK     391
#define P1_EDGES  8192
#define P1_THREADS 512
#define P2_THREADS 1024
#define UB        25000                              // gather_u blocks per slice (4 rows/block)
#define IT_SH     (50001 * 32)                       // it2 slice stride in f16 elements (3.2 MB)
#define CVT_GROUPS (NUM_ITEMS * 8)                  // 400000 half8 groups
#define CVT_BLOCKS ((CVT_GROUPS + P1_THREADS - 1) / P1_THREADS)  // 782

typedef _Float16 half8 __attribute__((ext_vector_type(8)));

union H8 { half8 v; int i[4]; };

// reduction across slot bits (8,16,32): for 8-slot geometry (gather_it/batch_score)
__device__ __forceinline__ half8 slot_reduce8(half8 acc) {
    H8 a; a.v = acc;
    H8 o;
    #pragma unroll
    for (int j = 0; j < 4; ++j) o.i[j] = __shfl_xor(a.i[j], 8, 64);
    a.v += o.v;
    #pragma unroll
    for (int j = 0; j < 4; ++j) o.i[j] = __shfl_xor(a.i[j], 16, 64);
    a.v += o.v;
    #pragma unroll
    for (int j = 0; j < 4; ++j) o.i[j] = __shfl_xor(a.i[j], 32, 64);
    a.v += o.v;
    return a.v;
}

// reduction across slot bits (4,8,16,32): for 16-slot geometry (gather_u slices)
__device__ __forceinline__ half8 slot_reduce16(half8 acc) {
    H8 a; a.v = acc;
    H8 o;
    #pragma unroll
    for (int j = 0; j < 4; ++j) o.i[j] = __shfl_xor(a.i[j], 4, 64);
    a.v += o.v;
    #pragma unroll
    for (int j = 0; j < 4; ++j) o.i[j] = __shfl_xor(a.i[j], 8, 64);
    a.v += o.v;
    #pragma unroll
    for (int j = 0; j < 4; ++j) o.i[j] = __shfl_xor(a.i[j], 16, 64);
    a.v += o.v;
    #pragma unroll
    for (int j = 0; j < 4; ++j) o.i[j] = __shfl_xor(a.i[j], 32, 64);
    a.v += o.v;
    return a.v;
}

// ---------- fused build: pass1 (blocks 0..399) + cvt (400..1181) + zero rows (1182) ----------
// it2 layout: [2][50001][32] f16 — slice s holds dims s*32..s*32+31; row 50000 = zero sentinel
__global__ void __launch_bounds__(P1_THREADS)
build_kernel(const int* __restrict__ rows, const int* __restrict__ cols,
             const float* __restrict__ itab, _Float16* __restrict__ it2,
             _Float16* __restrict__ w16,
             int* __restrict__ ucur, int* __restrict__ icur,
             int* __restrict__ rec_u, int* __restrict__ rec_i) {
    __shared__ int hu[400], hi[400], gu[400], gi[400];
    __shared__ int lbase[400], lcur[400];
    __shared__ int sc[512];
    __shared__ int recbuf[P1_EDGES];
    int t = threadIdx.x;

    if (blockIdx.x >= 400) {
        int b = blockIdx.x - 400;
        if (b < CVT_BLOCKS) {
            int i = b * P1_THREADS + t;
            if (i < CVT_GROUPS) {
                int item = i >> 3, g = i & 7;
                const float4* p = (const float4*)itab + 2 * i;
                float4 a = p[0], c = p[1];
                half8 o;
                o[0] = (_Float16)a.x; o[1] = (_Float16)a.y; o[2] = (_Float16)a.z; o[3] = (_Float16)a.w;
                o[4] = (_Float16)c.x; o[5] = (_Float16)c.y; o[6] = (_Float16)c.z; o[7] = (_Float16)c.w;
                *(half8*)(it2 + (g >> 2) * IT_SH + item * 32 + (g & 3) * 8) = o;
            }
        } else {
            if (t < 64) w16[(long long)NUM_USERS * EMBED + t] = (_Float16)0.f;
            else if (t < 128) {
                int idx = t - 64;                 // 0..63: two 32-elem sentinel rows
                it2[(idx >> 5) * IT_SH + 50000 * 32 + (idx & 31)] = (_Float16)0.f;
            }
        }
        return;
    }

    long long e0 = (long long)blockIdx.x * P1_EDGES;
    int er[16], ec[16];
    #pragma unroll
    for (int q = 0; q < 16; ++q) {
        er[q] = rows[e0 + t + q * P1_THREADS];
        ec[q] = cols[e0 + t + q * P1_THREADS];
    }

    for (int i = t; i < 400; i += P1_THREADS) { hu[i] = 0; hi[i] = 0; }
    __syncthreads();
    #pragma unroll
    for (int q = 0; q < 16; ++q) {
        atomicAdd(&hu[er[q] >> 8], 1);
        atomicAdd(&hi[ec[q] >> 7], 1);
    }
    __syncthreads();
    for (int i = t; i < 400; i += P1_THREADS) {
        int vr = (hu[i] + 15) & ~15;
        gu[i] = vr ? atomicAdd(&ucur[i], vr) : 0;
        vr = (hi[i] + 15) & ~15;
        gi[i] = vr ? atomicAdd(&icur[i], vr) : 0;
    }

    // ===== user phase =====
    __syncthreads();
    sc[t] = (t < 400) ? hu[t] : 0;
    __syncthreads();
    for (int o = 1; o < 512; o <<= 1) {
        int x = (t >= o) ? sc[t - o] : 0; __syncthreads();
        sc[t] += x; __syncthreads();
    }
    if (t < 400) { lbase[t] = sc[t] - hu[t]; lcur[t] = 0; }
    __syncthreads();
    #pragma unroll
    for (int q = 0; q < 16; ++q) {
        int b = er[q] >> 8;
        int p = lbase[b] + atomicAdd(&lcur[b], 1);
        recbuf[p] = (ec[q] << 8) | (er[q] & 255);
    }
    __syncthreads();
    sc[t] = (t < 400) ? ((hu[t] + 15) & ~15) : 0;
    __syncthreads();
    for (int o = 1; o < 512; o <<= 1) {
        int x = (t >= o) ? sc[t - o] : 0; __syncthreads();
        sc[t] += x; __syncthreads();
    }
    int total = sc[511];
    for (int o4 = t * 4; o4 < total; o4 += P1_THREADS * 4) {
        int lo = 0, hi_ = 399;
        while (lo < hi_) { int mid = (lo + hi_) >> 1; if (sc[mid] > o4) hi_ = mid; else lo = mid + 1; }
        int b = lo;
        int v = hu[b];
        int vr = (v + 15) & ~15;
        int j = o4 - (sc[b] - vr);
        int gpos = gu[b] + j;
        if (gpos + 3 < CAP) {
            int4 val;
            val.x = (j + 0 < v) ? recbuf[lbase[b] + j + 0] : -1;
            val.y = (j + 1 < v) ? recbuf[lbase[b] + j + 1] : -1;
            val.z = (j + 2 < v) ? recbuf[lbase[b] + j + 2] : -1;
            val.w = (j + 3 < v) ? recbuf[lbase[b] + j + 3] : -1;
            *(int4*)(rec_u + (long long)b * CAP + gpos) = val;
        } else {
            for (int k = 0; k < 4; ++k)
                if (gpos + k < CAP)
                    rec_u[(long long)b * CAP + gpos + k] = (j + k < v) ? recbuf[lbase[b] + j + k] : -1;
        }
    }

    // ===== item phase =====
    __syncthreads();
    sc[t] = (t < 400) ? hi[t] : 0;
    __syncthreads();
    for (int o = 1; o < 512; o <<= 1) {
        int x = (t >= o) ? sc[t - o] : 0; __syncthreads();
        sc[t] += x; __syncthreads();
    }
    if (t < 400) { lbase[t] = sc[t] - hi[t]; lcur[t] = 0; }
    __syncthreads();
    #pragma unroll
    for (int q = 0; q < 16; ++q) {
        int b = ec[q] >> 7;
        int p = lbase[b] + atomicAdd(&lcur[b], 1);
        recbuf[p] = (er[q] << 7) | (ec[q] & 127);
    }
    __syncthreads();
    sc[t] = (t < 400) ? ((hi[t] + 15) & ~15) : 0;
    __syncthreads();
    for (int o = 1; o < 512; o <<= 1) {
        int x = (t >= o) ? sc[t - o] : 0; __syncthreads();
        sc[t] += x; __syncthreads();
    }
    total = sc[511];
    for (int o4 = t * 4; o4 < total; o4 += P1_THREADS * 4) {
        int lo = 0, hi_ = 399;
        while (lo < hi_) { int mid = (lo + hi_) >> 1; if (sc[mid] > o4) hi_ = mid; else lo = mid + 1; }
        int b = lo;
        int v = hi[b];
        int vr = (v + 15) & ~15;
        int j = o4 - (sc[b] - vr);
        int gpos = gi[b] + j;
        if (gpos + 3 < CAP) {
            int4 val;
            val.x = (j + 0 < v) ? recbuf[lbase[b] + j + 0] : -1;
            val.y = (j + 1 < v) ? recbuf[lbase[b] + j + 1] : -1;
            val.z = (j + 2 < v) ? recbuf[lbase[b] + j + 2] : -1;
            val.w = (j + 3 < v) ? recbuf[lbase[b] + j + 3] : -1;
            *(int4*)(rec_i + (long long)b * CAP + gpos) = val;
        } else {
            for (int k = 0; k < 4; ++k)
                if (gpos + k < CAP)
                    rec_i[(long long)b * CAP + gpos + k] = (j + k < v) ? recbuf[lbase[b] + j + k] : -1;
        }
    }
}

// ---------- pass 2: fine sort in LDS; pad16 per row + pre-shifted byte offsets ----------
// SHIFT: 6 for users (64-B slice rows), 7 for items (128-B w rows)
template <int VBITS, int SHIFT>
__device__ __forceinline__ void pass2_body(int* __restrict__ rec, const int* __restrict__ cur,
                                           int* __restrict__ deg, int* __restrict__ off,
                                           float* __restrict__ inv32, int ncap, int b, int sentinel,
                                           int* buf, int* h, int* ex, int* cnt, int* sc) {
    const int V = 1 << VBITS, M = V - 1;
    int t = threadIdx.x;
    long long s = (long long)b * CAP;
    int n = cur[b]; if (n > CAP) n = CAP;
    int nv = (n + 3) >> 2;
    const int4* rec4 = (const int4*)(rec + s);
    for (int i = t; i < nv; i += P2_THREADS) {
        int4 v4 = rec4[i];
        buf[4 * i + 0] = v4.x; buf[4 * i + 1] = v4.y;
        buf[4 * i + 2] = v4.z; buf[4 * i + 3] = v4.w;
    }
    if (t < V) { h[t] = 0; cnt[t] = 0; }
    __syncthreads();
    for (int i = t; i < n; i += P2_THREADS) {
        int r = buf[i];
        if (r != -1) atomicAdd(&h[r & M], 1);
    }
    __syncthreads();
    // padded (x16) prefix scan
    if (t < V) sc[t] = (h[t] + 15) & ~15;
    __syncthreads();
    for (int o = 1; o < V; o <<= 1) {
        int x = (t >= o && t < V) ? sc[t - o] : 0;
        __syncthreads();
        if (t < V) sc[t] += x;
        __syncthreads();
    }
    if (t < V) {
        int ph = (h[t] + 15) & ~15;
        int pb = sc[t] - ph;          // padded exclusive prefix (multiple of 16)
        ex[t] = pb;
        int id = b * V + t;
        if (id < ncap) {
            int v = h[t];
            deg[id] = v;              // exact degree
            off[id] = (int)(s + pb);  // padded start (element index, x16 aligned)
            if (inv32) inv32[id] = v ? 1.0f / (float)v : 0.0f;
        }
        // sentinel fill for pad slots [h, ph)
        for (int j = h[t]; j < ph && pb + j < CAP; ++j) rec[s + pb + j] = sentinel;
    }
    __syncthreads();
    for (int i = t; i < n; i += P2_THREADS) {
        int r = buf[i];
        if (r == -1) continue;
        int k = r & M;
        int rnk = atomicAdd(&cnt[k], 1);
        int p = ex[k] + rnk;
        if (p < CAP)
            rec[s + p] = (int)((((unsigned)r) >> VBITS) << SHIFT);   // pre-shifted byte offset
    }
}

__global__ void __launch_bounds__(P2_THREADS)
pass2_kernel(int* __restrict__ rec_u, const int* __restrict__ ucur,
             int* __restrict__ udeg, int* __restrict__ uoff, float* __restrict__ inv32,
             int* __restrict__ rec_i, const int* __restrict__ icur,
             int* __restrict__ ideg, int* __restrict__ ioff) {
    __shared__ int buf[CAP];
    __shared__ int h[256], ex[256], cnt[256], sc[256];
    if (blockIdx.x < NBUCK)
        pass2_body<8, 6>(rec_u, ucur, udeg, uoff, inv32, NUM_USERS, blockIdx.x,
                         NUM_ITEMS << 6, buf, h, ex, cnt, sc);
    else
        pass2_body<7, 7>(rec_i, icur, ideg, ioff, (float*)nullptr, NUM_ITEMS,
                         blockIdx.x - NBUCK, NUM_USERS << 7, buf, h, ex, cnt, sc);
}

// ---------- gather SpMM (u), dim-sliced: table slice 3.2 MB = L2-resident ----------
// grid = 2*UB blocks; slice = blockIdx>=UB (block-order gives phase separation).
// 16 slots x 4 h-lanes, 64-B rows (one cache line per edge).
__global__ void gather_u(const int* __restrict__ uoff, const int* __restrict__ udeg,
                         const int* __restrict__ csr_boff, const float* __restrict__ inv32,
                         const _Float16* __restrict__ it2, _Float16* __restrict__ w) {
    int bb = blockIdx.x;
    int s = 0;
    if (bb >= UB) { s = 1; bb -= UB; }
    int row = bb * 4 + (threadIdx.x >> 6);
    if (row >= NUM_USERS) return;
    int lane = threadIdx.x & 63;
    int slot = lane >> 2;
    int h    = lane & 3;
    int start = uoff[row];
    int pend = start + ((udeg[row] + 15) & ~15);
    const char* tb = (const char*)(it2 + s * IT_SH);
    unsigned hoff = (unsigned)(h << 4);
    half8 acc0 = {}, acc1 = {};
    int k = start;
    for (; k + 64 <= pend; k += 64) {
        int4 o = *(const int4*)(csr_boff + k + slot * 4);
        half8 x0 = *(const half8*)(tb + ((unsigned)o.x + hoff));
        half8 x1 = *(const half8*)(tb + ((unsigned)o.y + hoff));
        half8 x2 = *(const half8*)(tb + ((unsigned)o.z + hoff));
        half8 x3 = *(const half8*)(tb + ((unsigned)o.w + hoff));
        acc0 += x0 + x1;
        acc1 += x2 + x3;
    }
    if (k + 32 <= pend) {
        int2 o2 = *(const int2*)(csr_boff + k + slot * 2);
        half8 x0 = *(const half8*)(tb + ((unsigned)o2.x + hoff));
        half8 x1 = *(const half8*)(tb + ((unsigned)o2.y + hoff));
        acc0 += x0 + x1;
        k += 32;
    }
    if (k < pend) {
        int o1 = csr_boff[k + slot];
        acc1 += *(const half8*)(tb + ((unsigned)o1 + hoff));
    }
    half8 r = slot_reduce16(acc0 + acc1);
    if (lane < 4) {
        float v = inv32[row];
        float v2 = v * v;
        half8 ow;
        #pragma unroll
        for (int j = 0; j < 8; ++j) ow[j] = (_Float16)((float)r[j] * v2);
        *(half8*)(w + (long long)row * EMBED + s * 32 + (h << 3)) = ow;
    }
}

// ---------- gather SpMM (it): R1 shape (full 128-B w rows), writes sliced it2 ----------
__global__ void gather_it(const int* __restrict__ ioff, const int* __restrict__ ideg,
                          const int* __restrict__ csc_boff,
                          const _Float16* __restrict__ w, _Float16* __restrict__ it2) {
    int col = blockIdx.x * 4 + (threadIdx.x >> 6);
    if (col >= NUM_ITEMS) return;
    int lane = threadIdx.x & 63;
    int slot = lane >> 3;
    int h    = lane & 7;
    int start = ioff[col];
    int pend = start + ((ideg[col] + 15) & ~15);
    const char* wb = (const char*)w;
    unsigned hoff = (unsigned)(h << 4);
    half8 acc = {};
    int k = start;
    for (; k + 32 <= pend; k += 32) {
        int4 o = *(const int4*)(csc_boff + k + slot * 4);
        half8 x0 = *(const half8*)(wb + ((unsigned)o.x + hoff));
        half8 x1 = *(const half8*)(wb + ((unsigned)o.y + hoff));
        half8 x2 = *(const half8*)(wb + ((unsigned)o.z + hoff));
        half8 x3 = *(const half8*)(wb + ((unsigned)o.w + hoff));
        acc += (x0 + x1) + (x2 + x3);
    }
    if (k < pend) {
        int2 o2 = *(const int2*)(csc_boff + k + slot * 2);
        half8 x0 = *(const half8*)(wb + ((unsigned)o2.x + hoff));
        half8 x1 = *(const half8*)(wb + ((unsigned)o2.y + hoff));
        acc += x0 + x1;
    }
    half8 r = slot_reduce8(acc);
    if (lane < 8)
        *(half8*)(it2 + (h >> 2) * IT_SH + col * 32 + (h & 3) * 8) = r;
}

// ---------- fused last layer: it3 row in registers -> dot with deg*w3 -> sigmoid ----------
__global__ void batch_score(const int* __restrict__ ioff, const int* __restrict__ ideg,
                            const int* __restrict__ csc_boff, const _Float16* __restrict__ w,
                            const int* __restrict__ udeg,
                            const int* __restrict__ uidx, const int* __restrict__ iidx,
                            float* __restrict__ out) {
    int b = blockIdx.x * 4 + (threadIdx.x >> 6);
    if (b >= BATCH) return;
    int lane = threadIdx.x & 63;
    int col = iidx[b];
    int slot = lane >> 3;
    int h    = lane & 7;
    int start = ioff[col];
    int pend = start + ((ideg[col] + 15) & ~15);
    const char* wb = (const char*)w;
    unsigned hoff = (unsigned)(h << 4);
    half8 acc = {};
    int k = start;
    for (; k + 32 <= pend; k += 32) {
        int4 o = *(const int4*)(csc_boff + k + slot * 4);
        half8 x0 = *(const half8*)(wb + ((unsigned)o.x + hoff));
        half8 x1 = *(const half8*)(wb + ((unsigned)o.y + hoff));
        half8 x2 = *(const half8*)(wb + ((unsigned)o.z + hoff));
        half8 x3 = *(const half8*)(wb + ((unsigned)o.w + hoff));
        acc += (x0 + x1) + (x2 + x3);
    }
    if (k < pend) {
        int2 o2 = *(const int2*)(csc_boff + k + slot * 2);
        half8 x0 = *(const half8*)(wb + ((unsigned)o2.x + hoff));
        half8 x1 = *(const half8*)(wb + ((unsigned)o2.y + hoff));
        acc += x0 + x1;
    }
    half8 r = slot_reduce8(acc);
    int ui = uidx[b];
    half8 wv = *(const half8*)(w + (long long)ui * EMBED + (h << 3));
    float p = 0.f;
    #pragma unroll
    for (int j = 0; j < 8; ++j) p += (float)r[j] * (float)wv[j];
    p += __shfl_xor(p, 1, 64);
    p += __shfl_xor(p, 2, 64);
    p += __shfl_xor(p, 4, 64);
    if (lane == 0) {
        float s = p * (float)udeg[ui];   // u3 = deg * w3
        out[b] = 1.0f / (1.0f + expf(-s));
    }
}

extern "C" void kernel_launch(void* const* d_in, const int* in_sizes, int n_in,
                              void* d_out, int out_size, void* d_ws, size_t ws_size,
                              hipStream_t stream) {
    const float* item_table = (const float*)d_in[1];
    const int*   rows       = (const int*)d_in[2];
    const int*   cols       = (const int*)d_in[3];
    const int*   uidx       = (const int*)d_in[4];
    const int*   iidx       = (const int*)d_in[5];
    float* out = (float*)d_out;

    // workspace layout (byte offsets) — R13 layout; it2 occupies the old it16 region
    char* base = (char*)d_ws;
    int*   udeg  = (int*)(base + 0);                    // 100000 i
    int*   ideg  = (int*)(base +   400000);             // 50000 i
    int*   uoff  = (int*)(base +   600000);             // 100000 i
    int*   ioff  = (int*)(base +  1000000);             // 50000 i
    float* inv32 = (float*)(base + 1200000);            // 100000 f
    int*   ucur  = (int*)(base +  1600000);             // 400 i
    int*   icur  = (int*)(base +  1601600);             // 400 i (contiguous)
    int*   rec_u = (int*)(base +  1720320);             // 400*CAP i = 20.48 MB
    int*   rec_i = (int*)(base + 22200320);             // 400*CAP i = 20.48 MB
    _Float16* w16 = (_Float16*)(base + 42680320);       // (100000+1)*64 h
    _Float16* it2 = (_Float16*)(base + 55480448);       // 2*(50000+1)*32 h (same bytes as old it16)
    // ends ~61.9 MB

    // cursors must be zero BEFORE build_kernel (same-dispatch ordering is undefined)
    (void)hipMemsetAsync(ucur, 0, 3200, stream);

    // ---- fused build: pass1 + cvt + zero-rows in one dispatch ----
    build_kernel<<<400 + CVT_BLOCKS + 1, P1_THREADS, 0, stream>>>(
        rows, cols, item_table, it2, w16, ucur, icur, rec_u, rec_i);
    pass2_kernel<<<NBUCK * 2, P2_THREADS, 0, stream>>>(rec_u, ucur, udeg, uoff, inv32,
                                                       rec_i, icur, ideg, ioff);

    // ---- propagation ----
    const int iblocks = (NUM_ITEMS + 3) / 4;
    for (int l = 0; l < 3; ++l) {
        gather_u<<<2 * UB, 256, 0, stream>>>(uoff, udeg, rec_u, inv32, it2, w16);
        if (l < 2)
            gather_it<<<iblocks, 256, 0, stream>>>(ioff, ideg, rec_i, w16, it2);
    }
    batch_score<<<BATCH / 4, 256, 0, stream>>>(ioff, ideg, rec_i, w16, udeg,
                                               uidx, iidx, out);
}

// Round 5
// 397.132 us; speedup vs baseline: 1.2051x; 1.2051x over previous
//
#include <hip/hip_runtime.h>
#include <math.h>

#define NUM_USERS 100000
#define NUM_ITEMS 50000
#define EMBED     64
#define NUM_EDGES 3276800
#define BATCH     16384
#define CAP       12800       // pass1 padded mean ~11380 + ~11 sigma; pass2 pad16 compacted fits
#define NBUCK     391
#define P1_EDGES  8192
#define P1_THREADS 512
#define P2_THREADS 1024
#define CVT_GROUPS (NUM_ITEMS * 8)                  // 400000 half8 groups
#define CVT_BLOCKS ((CVT_GROUPS + P1_THREADS - 1) / P1_THREADS)  // 782

typedef _Float16 half8 __attribute__((ext_vector_type(8)));

union H8 { half8 v; int i[4]; };

// packed-f16 reduction across slot bits (8,16,32): 12 shfl + 12 v_pk_add_f16
__device__ __forceinline__ half8 slot_reduce(half8 acc) {
    H8 a; a.v = acc;
    H8 o;
    #pragma unroll
    for (int j = 0; j < 4; ++j) o.i[j] = __shfl_xor(a.i[j], 8, 64);
    a.v += o.v;
    #pragma unroll
    for (int j = 0; j < 4; ++j) o.i[j] = __shfl_xor(a.i[j], 16, 64);
    a.v += o.v;
    #pragma unroll
    for (int j = 0; j < 4; ++j) o.i[j] = __shfl_xor(a.i[j], 32, 64);
    a.v += o.v;
    return a.v;
}

// hierarchical inclusive scan over 512 threads (8 waves): 6 shfl + 1 barrier
// caller must ensure swv is not concurrently reused (>=1 barrier between calls)
__device__ __forceinline__ unsigned scan_incl_512(unsigned val, unsigned* swv, int t) {
    unsigned x = val;
    #pragma unroll
    for (int o = 1; o < 64; o <<= 1) {
        unsigned y = __shfl_up(x, o, 64);
        if ((t & 63) >= o) x += y;
    }
    if ((t & 63) == 63) swv[t >> 6] = x;
    __syncthreads();
    unsigned base = 0;
    int w = t >> 6;
    #pragma unroll
    for (int i = 0; i < 7; ++i)
        base += (i < w) ? swv[i] : 0;
    return x + base;
}

// ---------- fused build: pass1 (blocks 0..399) + cvt (400..1181) + zero rows (1182) ----------
__global__ void __launch_bounds__(P1_THREADS)
build_kernel(const int* __restrict__ rows, const int* __restrict__ cols,
             const float* __restrict__ itab, _Float16* __restrict__ it16,
             _Float16* __restrict__ w16,
             int* __restrict__ ucur, int* __restrict__ icur,
             int* __restrict__ rec_u, int* __restrict__ rec_i) {
    __shared__ int hu[400], hi[400], gu[400], gi[400];
    __shared__ int lbase[400], lcur[400];
    __shared__ unsigned scp[512];      // packed inclusive scan: (pad16 << 16) | raw
    __shared__ unsigned swv[8];
    __shared__ int recbuf[P1_EDGES];
    int t = threadIdx.x;

    if (blockIdx.x >= 400) {
        int b = blockIdx.x - 400;
        if (b < CVT_BLOCKS) {
            int i = b * P1_THREADS + t;
            if (i < CVT_GROUPS) {
                const float4* p = (const float4*)itab + 2 * i;
                float4 a = p[0], c = p[1];
                half8 o;
                o[0] = (_Float16)a.x; o[1] = (_Float16)a.y; o[2] = (_Float16)a.z; o[3] = (_Float16)a.w;
                o[4] = (_Float16)c.x; o[5] = (_Float16)c.y; o[6] = (_Float16)c.z; o[7] = (_Float16)c.w;
                ((half8*)it16)[i] = o;
            }
        } else {
            if (t < 64) w16[(long long)NUM_USERS * EMBED + t] = (_Float16)0.f;
            else if (t < 128) it16[(long long)NUM_ITEMS * EMBED + (t - 64)] = (_Float16)0.f;
        }
        return;
    }

    long long e0 = (long long)blockIdx.x * P1_EDGES;
    int er[16], ec[16];
    #pragma unroll
    for (int q = 0; q < 16; ++q) {
        er[q] = rows[e0 + t + q * P1_THREADS];
        ec[q] = cols[e0 + t + q * P1_THREADS];
    }

    for (int i = t; i < 400; i += P1_THREADS) { hu[i] = 0; hi[i] = 0; }
    __syncthreads();
    #pragma unroll
    for (int q = 0; q < 16; ++q) {
        atomicAdd(&hu[er[q] >> 8], 1);
        atomicAdd(&hi[ec[q] >> 7], 1);
    }
    __syncthreads();
    for (int i = t; i < 400; i += P1_THREADS) {
        int vr = (hu[i] + 15) & ~15;
        gu[i] = vr ? atomicAdd(&ucur[i], vr) : 0;
        vr = (hi[i] + 15) & ~15;
        gi[i] = vr ? atomicAdd(&icur[i], vr) : 0;
    }

    // ===== user phase =====
    {
        unsigned hv = (t < 400) ? (unsigned)hu[t] : 0u;
        unsigned val = (((hv + 15u) & ~15u) << 16) | hv;
        unsigned incl = scan_incl_512(val, swv, t);           // 1 barrier inside
        scp[t] = incl;
        if (t < 400) { lbase[t] = (int)(incl & 0xffffu) - (int)hv; lcur[t] = 0; }
    }
    __syncthreads();
    #pragma unroll
    for (int q = 0; q < 16; ++q) {
        int b = er[q] >> 8;
        int p = lbase[b] + atomicAdd(&lcur[b], 1);
        recbuf[p] = (ec[q] << 8) | (er[q] & 255);
    }
    __syncthreads();
    {
        int total = (int)(scp[511] >> 16);
        for (int o4 = t * 4; o4 < total; o4 += P1_THREADS * 4) {
            int lo = 0, hi_ = 399;
            while (lo < hi_) { int mid = (lo + hi_) >> 1; if ((int)(scp[mid] >> 16) > o4) hi_ = mid; else lo = mid + 1; }
            int b = lo;
            int v = hu[b];
            int vr = (v + 15) & ~15;
            int j = o4 - ((int)(scp[b] >> 16) - vr);
            int gpos = gu[b] + j;
            if (gpos + 3 < CAP) {
                int4 val;
                val.x = (j + 0 < v) ? recbuf[lbase[b] + j + 0] : -1;
                val.y = (j + 1 < v) ? recbuf[lbase[b] + j + 1] : -1;
                val.z = (j + 2 < v) ? recbuf[lbase[b] + j + 2] : -1;
                val.w = (j + 3 < v) ? recbuf[lbase[b] + j + 3] : -1;
                *(int4*)(rec_u + (long long)b * CAP + gpos) = val;
            } else {
                for (int k = 0; k < 4; ++k)
                    if (gpos + k < CAP)
                        rec_u[(long long)b * CAP + gpos + k] = (j + k < v) ? recbuf[lbase[b] + j + k] : -1;
            }
        }
    }
    __syncthreads();

    // ===== item phase =====
    {
        unsigned hv = (t < 400) ? (unsigned)hi[t] : 0u;
        unsigned val = (((hv + 15u) & ~15u) << 16) | hv;
        unsigned incl = scan_incl_512(val, swv, t);
        scp[t] = incl;
        if (t < 400) { lbase[t] = (int)(incl & 0xffffu) - (int)hv; lcur[t] = 0; }
    }
    __syncthreads();
    #pragma unroll
    for (int q = 0; q < 16; ++q) {
        int b = ec[q] >> 7;
        int p = lbase[b] + atomicAdd(&lcur[b], 1);
        recbuf[p] = (er[q] << 7) | (ec[q] & 127);
    }
    __syncthreads();
    {
        int total = (int)(scp[511] >> 16);
        for (int o4 = t * 4; o4 < total; o4 += P1_THREADS * 4) {
            int lo = 0, hi_ = 399;
            while (lo < hi_) { int mid = (lo + hi_) >> 1; if ((int)(scp[mid] >> 16) > o4) hi_ = mid; else lo = mid + 1; }
            int b = lo;
            int v = hi[b];
            int vr = (v + 15) & ~15;
            int j = o4 - ((int)(scp[b] >> 16) - vr);
            int gpos = gi[b] + j;
            if (gpos + 3 < CAP) {
                int4 val;
                val.x = (j + 0 < v) ? recbuf[lbase[b] + j + 0] : -1;
                val.y = (j + 1 < v) ? recbuf[lbase[b] + j + 1] : -1;
                val.z = (j + 2 < v) ? recbuf[lbase[b] + j + 2] : -1;
                val.w = (j + 3 < v) ? recbuf[lbase[b] + j + 3] : -1;
                *(int4*)(rec_i + (long long)b * CAP + gpos) = val;
            } else {
                for (int k = 0; k < 4; ++k)
                    if (gpos + k < CAP)
                        rec_i[(long long)b * CAP + gpos + k] = (j + k < v) ? recbuf[lbase[b] + j + k] : -1;
            }
        }
    }
}

// ---------- pass 2: fine sort in LDS; per-row pad to x16 with sentinel + pre-shifted byte offsets ----------
template <int VBITS>
__device__ __forceinline__ void pass2_body(int* __restrict__ rec, const int* __restrict__ cur,
                                           int* __restrict__ deg, int* __restrict__ off,
                                           float* __restrict__ inv32, int ncap, int b, int sentinel,
                                           int* buf, int* h, int* ex, int* cnt, unsigned* swv) {
    const int V = 1 << VBITS, M = V - 1;
    int t = threadIdx.x;
    long long s = (long long)b * CAP;
    int n = cur[b]; if (n > CAP) n = CAP;
    int nv = (n + 3) >> 2;
    const int4* rec4 = (const int4*)(rec + s);
    for (int i = t; i < nv; i += P2_THREADS) {
        int4 v4 = rec4[i];
        buf[4 * i + 0] = v4.x; buf[4 * i + 1] = v4.y;
        buf[4 * i + 2] = v4.z; buf[4 * i + 3] = v4.w;
    }
    if (t < V) { h[t] = 0; cnt[t] = 0; }
    __syncthreads();
    for (int i = t; i < n; i += P2_THREADS) {
        int r = buf[i];
        if (r != -1) atomicAdd(&h[r & M], 1);
    }
    __syncthreads();
    // hierarchical padded (x16) scan over V values: 1 barrier
    unsigned ph = 0, x = 0;
    {
        unsigned hv = (t < V) ? (unsigned)h[t] : 0u;
        ph = (hv + 15u) & ~15u;
        x = ph;
        #pragma unroll
        for (int o = 1; o < 64; o <<= 1) {
            unsigned y = __shfl_up(x, o, 64);
            if ((t & 63) >= o) x += y;
        }
        if ((t & 63) == 63 && t < V) swv[t >> 6] = x;
    }
    __syncthreads();
    if (t < V) {
        unsigned base = 0;
        int w = t >> 6;
        #pragma unroll
        for (int i = 0; i < (V >> 6); ++i)
            base += (i < w) ? swv[i] : 0;
        int pb = (int)(x + base - ph);    // padded exclusive prefix (multiple of 16)
        ex[t] = pb;
        int id = b * V + t;
        if (id < ncap) {
            int v = h[t];
            deg[id] = v;              // exact degree
            off[id] = (int)(s + pb);  // padded start (element index, x16 aligned)
            if (inv32) inv32[id] = v ? 1.0f / (float)v : 0.0f;
        }
        // sentinel fill for pad slots [h, ph)
        for (int j = h[t]; j < (int)ph && pb + j < CAP; ++j) rec[s + pb + j] = sentinel;
    }
    __syncthreads();
    for (int i = t; i < n; i += P2_THREADS) {
        int r = buf[i];
        if (r == -1) continue;
        int k = r & M;
        int rnk = atomicAdd(&cnt[k], 1);
        int p = ex[k] + rnk;
        if (p < CAP)
            rec[s + p] = (int)((((unsigned)r) >> VBITS) << 7);   // pre-shifted byte offset (row stride 128B)
    }
}

__global__ void __launch_bounds__(P2_THREADS)
pass2_kernel(int* __restrict__ rec_u, const int* __restrict__ ucur,
             int* __restrict__ udeg, int* __restrict__ uoff, float* __restrict__ inv32,
             int* __restrict__ rec_i, const int* __restrict__ icur,
             int* __restrict__ ideg, int* __restrict__ ioff) {
    __shared__ int buf[CAP];
    __shared__ int h[256], ex[256], cnt[256];
    __shared__ unsigned swv[8];
    if (blockIdx.x < NBUCK)
        pass2_body<8>(rec_u, ucur, udeg, uoff, inv32, NUM_USERS, blockIdx.x,
                      NUM_ITEMS << 7, buf, h, ex, cnt, swv);
    else
        pass2_body<7>(rec_i, icur, ideg, ioff, (float*)nullptr, NUM_ITEMS,
                      blockIdx.x - NBUCK, NUM_USERS << 7, buf, h, ex, cnt, swv);
}

// ---------- gather SpMM (u): clamp-free, padded-adjacency, pre-shifted offsets (R1 shape) ----------
__global__ void gather_u(const int* __restrict__ uoff, const int* __restrict__ udeg,
                         const int* __restrict__ csr_boff, const float* __restrict__ inv32,
                         const _Float16* __restrict__ it, _Float16* __restrict__ w) {
    int row = blockIdx.x * 4 + (threadIdx.x >> 6);
    if (row >= NUM_USERS) return;
    int lane = threadIdx.x & 63;
    int slot = lane >> 3;
    int h    = lane & 7;
    int start = uoff[row];
    int pend = start + ((udeg[row] + 15) & ~15);
    const char* itb = (const char*)it;
    unsigned hoff = (unsigned)(h << 4);
    half8 acc = {};
    int k = start;
    for (; k + 32 <= pend; k += 32) {
        int4 o = *(const int4*)(csr_boff + k + slot * 4);
        half8 x0 = *(const half8*)(itb + ((unsigned)o.x + hoff));
        half8 x1 = *(const half8*)(itb + ((unsigned)o.y + hoff));
        half8 x2 = *(const half8*)(itb + ((unsigned)o.z + hoff));
        half8 x3 = *(const half8*)(itb + ((unsigned)o.w + hoff));
        acc += (x0 + x1) + (x2 + x3);
    }
    if (k < pend) {
        int2 o2 = *(const int2*)(csr_boff + k + slot * 2);
        half8 x0 = *(const half8*)(itb + ((unsigned)o2.x + hoff));
        half8 x1 = *(const half8*)(itb + ((unsigned)o2.y + hoff));
        acc += x0 + x1;
    }
    half8 r = slot_reduce(acc);
    if (lane < 8) {
        float v = inv32[row];
        float v2 = v * v;
        half8 ow;
        #pragma unroll
        for (int j = 0; j < 8; ++j) ow[j] = (_Float16)((float)r[j] * v2);
        *(half8*)(w + (long long)row * EMBED + (lane << 3)) = ow;
    }
}

// ---------- gather SpMM (it): clamp-free, padded-adjacency (R1 shape) ----------
__global__ void gather_it(const int* __restrict__ ioff, const int* __restrict__ ideg,
                          const int* __restrict__ csc_boff,
                          const _Float16* __restrict__ w, _Float16* __restrict__ it) {
    int col = blockIdx.x * 4 + (threadIdx.x >> 6);
    if (col >= NUM_ITEMS) return;
    int lane = threadIdx.x & 63;
    int slot = lane >> 3;
    int h    = lane & 7;
    int start = ioff[col];
    int pend = start + ((ideg[col] + 15) & ~15);
    const char* wb = (const char*)w;
    unsigned hoff = (unsigned)(h << 4);
    half8 acc = {};
    int k = start;
    for (; k + 32 <= pend; k += 32) {
        int4 o = *(const int4*)(csc_boff + k + slot * 4);
        half8 x0 = *(const half8*)(wb + ((unsigned)o.x + hoff));
        half8 x1 = *(const half8*)(wb + ((unsigned)o.y + hoff));
        half8 x2 = *(const half8*)(wb + ((unsigned)o.z + hoff));
        half8 x3 = *(const half8*)(wb + ((unsigned)o.w + hoff));
        acc += (x0 + x1) + (x2 + x3);
    }
    if (k < pend) {
        int2 o2 = *(const int2*)(csc_boff + k + slot * 2);
        half8 x0 = *(const half8*)(wb + ((unsigned)o2.x + hoff));
        half8 x1 = *(const half8*)(wb + ((unsigned)o2.y + hoff));
        acc += x0 + x1;
    }
    half8 r = slot_reduce(acc);
    if (lane < 8)
        *(half8*)(it + (long long)col * EMBED + (lane << 3)) = r;
}

// ---------- fused last layer: it3 row in registers -> dot with deg*w3 -> sigmoid ----------
__global__ void batch_score(const int* __restrict__ ioff, const int* __restrict__ ideg,
                            const int* __restrict__ csc_boff, const _Float16* __restrict__ w,
                            const int* __restrict__ udeg,
                            const int* __restrict__ uidx, const int* __restrict__ iidx,
                            float* __restrict__ out) {
    int b = blockIdx.x * 4 + (threadIdx.x >> 6);
    if (b >= BATCH) return;
    int lane = threadIdx.x & 63;
    int col = iidx[b];
    int slot = lane >> 3;
    int h    = lane & 7;
    int start = ioff[col];
    int pend = start + ((ideg[col] + 15) & ~15);
    const char* wb = (const char*)w;
    unsigned hoff = (unsigned)(h << 4);
    half8 acc = {};
    int k = start;
    for (; k + 32 <= pend; k += 32) {
        int4 o = *(const int4*)(csc_boff + k + slot * 4);
        half8 x0 = *(const half8*)(wb + ((unsigned)o.x + hoff));
        half8 x1 = *(const half8*)(wb + ((unsigned)o.y + hoff));
        half8 x2 = *(const half8*)(wb + ((unsigned)o.z + hoff));
        half8 x3 = *(const half8*)(wb + ((unsigned)o.w + hoff));
        acc += (x0 + x1) + (x2 + x3);
    }
    if (k < pend) {
        int2 o2 = *(const int2*)(csc_boff + k + slot * 2);
        half8 x0 = *(const half8*)(wb + ((unsigned)o2.x + hoff));
        half8 x1 = *(const half8*)(wb + ((unsigned)o2.y + hoff));
        acc += x0 + x1;
    }
    half8 r = slot_reduce(acc);
    int ui = uidx[b];
    half8 wv = *(const half8*)(w + (long long)ui * EMBED + (h << 3));
    float p = 0.f;
    #pragma unroll
    for (int j = 0; j < 8; ++j) p += (float)r[j] * (float)wv[j];
    p += __shfl_xor(p, 1, 64);
    p += __shfl_xor(p, 2, 64);
    p += __shfl_xor(p, 4, 64);
    if (lane == 0) {
        float s = p * (float)udeg[ui];   // u3 = deg * w3
        out[b] = 1.0f / (1.0f + expf(-s));
    }
}

extern "C" void kernel_launch(void* const* d_in, const int* in_sizes, int n_in,
                              void* d_out, int out_size, void* d_ws, size_t ws_size,
                              hipStream_t stream) {
    const float* item_table = (const float*)d_in[1];
    const int*   rows       = (const int*)d_in[2];
    const int*   cols       = (const int*)d_in[3];
    const int*   uidx       = (const int*)d_in[4];
    const int*   iidx       = (const int*)d_in[5];
    float* out = (float*)d_out;

    // workspace layout (byte offsets) — R13 layout
    char* base = (char*)d_ws;
    int*   udeg  = (int*)(base + 0);                    // 100000 i
    int*   ideg  = (int*)(base +   400000);             // 50000 i
    int*   uoff  = (int*)(base +   600000);             // 100000 i
    int*   ioff  = (int*)(base +  1000000);             // 50000 i
    float* inv32 = (float*)(base + 1200000);            // 100000 f
    int*   ucur  = (int*)(base +  1600000);             // 400 i
    int*   icur  = (int*)(base +  1601600);             // 400 i (contiguous)
    int*   rec_u = (int*)(base +  1720320);             // 400*CAP i = 20.48 MB
    int*   rec_i = (int*)(base + 22200320);             // 400*CAP i = 20.48 MB
    _Float16* w16  = (_Float16*)(base + 42680320);      // (100000+1)*64 h
    _Float16* it16 = (_Float16*)(base + 55480448);      // (50000+1)*64 h
    // ends ~61.9 MB

    // cursors must be zero BEFORE build_kernel (same-dispatch ordering is undefined)
    (void)hipMemsetAsync(ucur, 0, 3200, stream);

    // ---- fused build: pass1 + cvt + zero-rows in one dispatch ----
    build_kernel<<<400 + CVT_BLOCKS + 1, P1_THREADS, 0, stream>>>(
        rows, cols, item_table, it16, w16, ucur, icur, rec_u, rec_i);
    pass2_kernel<<<NBUCK * 2, P2_THREADS, 0, stream>>>(rec_u, ucur, udeg, uoff, inv32,
                                                       rec_i, icur, ideg, ioff);

    // ---- propagation ----
    const int ublocks = (NUM_USERS + 3) / 4;
    const int iblocks = (NUM_ITEMS + 3) / 4;
    for (int l = 0; l < 3; ++l) {
        gather_u<<<ublocks, 256, 0, stream>>>(uoff, udeg, rec_u, inv32, it16, w16);
        if (l < 2)
            gather_it<<<iblocks, 256, 0, stream>>>(ioff, ideg, rec_i, w16, it16);
    }
    batch_score<<<BATCH / 4, 256, 0, stream>>>(ioff, ideg, rec_i, w16, udeg,
                                               uidx, iidx, out);
}